// Round 5
// baseline (403.392 us; speedup 1.0000x reference)
//
#include <hip/hip_runtime.h>
#include <hip/hip_bf16.h>

// Sizes (fixed by problem)
#define BATCH 8
#define CDIM  512
#define NPOS  4096
#define KDQK  64
#define ODIM  512

typedef __attribute__((ext_vector_type(8)))  short short8v;   // 8 bf16 (MFMA A/B frag)
typedef __attribute__((ext_vector_type(16))) float f32x16;    // MFMA 32x32 C/D frag

static __device__ __forceinline__ unsigned short f2bf(float f) {
    union { __hip_bfloat16 h; unsigned short u; } cv;
    cv.h = __float2bfloat16(f);
    return cv.u;
}
static __device__ __forceinline__ float bf2f(unsigned short u) {
    union { unsigned short u; __hip_bfloat16 h; } cv;
    cv.u = u;
    return __bfloat162float(cv.h);
}

// async global->LDS 16B (wave-uniform LDS base + lane*16, per-lane global src)
static __device__ __forceinline__ void gload_lds16(const unsigned short* g, unsigned short* s) {
    __builtin_amdgcn_global_load_lds((const __attribute__((address_space(1))) unsigned int*)g,
                                     (__attribute__((address_space(3))) unsigned int*)s, 16, 0, 0);
}

static __device__ __forceinline__ int cvtpk(float a, float b) {
    int r;
    asm("v_cvt_pk_bf16_f32 %0, %1, %2" : "=v"(r) : "v"(a), "v"(b));
    return r;
}

#if __has_builtin(__builtin_amdgcn_exp2f)
static __device__ __forceinline__ float exp2_raw(float x) { return __builtin_amdgcn_exp2f(x); }
#else
static __device__ __forceinline__ float exp2_raw(float x) { return exp2f(x); }
#endif

// ---------------------------------------------------------------------------
// Kernel 1: convert q_w/k_w/v_w fp32 -> bf16 into workspace
// (wq and wk land contiguously -> stacked [128][512] matrix for fused QK proj)
// ---------------------------------------------------------------------------
__global__ __launch_bounds__(256) void wconv_kernel(const float* __restrict__ qw,
                                                    const float* __restrict__ kw,
                                                    const float* __restrict__ vw,
                                                    unsigned short* __restrict__ wq,
                                                    unsigned short* __restrict__ wk,
                                                    unsigned short* __restrict__ wv) {
    int idx = blockIdx.x * 256 + threadIdx.x;
    if (idx < 32768)        wq[idx]          = f2bf(qw[idx]);
    else if (idx < 65536)   wk[idx - 32768]  = f2bf(kw[idx - 32768]);
    else if (idx < 327680)  wv[idx - 65536]  = f2bf(vw[idx - 65536]);
}

// ---------------------------------------------------------------------------
// Kernel 2: x [B][C][N] fp32 -> xT [B][N][C] bf16   (64x64 tiles via LDS)
// ---------------------------------------------------------------------------
__global__ __launch_bounds__(256) void xpose_kernel(const float* __restrict__ x,
                                                    unsigned short* __restrict__ xT) {
    __shared__ float xs[64][65];
    const int b = blockIdx.z, c0 = blockIdx.y * 64, n0 = blockIdx.x * 64;
    const int t = threadIdx.x;
    #pragma unroll
    for (int it = 0; it < 4; ++it) {
        int lin = it * 256 + t;
        int c = lin >> 4, nq = lin & 15;
        const float4 v = *reinterpret_cast<const float4*>(
            x + ((size_t)(b * CDIM + c0 + c) * NPOS + n0 + nq * 4));
        xs[c][nq * 4 + 0] = v.x; xs[c][nq * 4 + 1] = v.y;
        xs[c][nq * 4 + 2] = v.z; xs[c][nq * 4 + 3] = v.w;
    }
    __syncthreads();
    #pragma unroll
    for (int it = 0; it < 4; ++it) {
        int lin = it * 256 + t;
        int n = lin >> 4, cq = lin & 15;
        ushort4 u;
        u.x = f2bf(xs[cq * 4 + 0][n]); u.y = f2bf(xs[cq * 4 + 1][n]);
        u.z = f2bf(xs[cq * 4 + 2][n]); u.w = f2bf(xs[cq * 4 + 3][n]);
        *reinterpret_cast<ushort4*>(xT + ((size_t)(b * NPOS + n0 + n) * CDIM + c0 + cq * 4)) = u;
    }
}

// ---------------------------------------------------------------------------
// Kernel 3: projection GEMM, 128x128 tile, BK=64, dbuf global_load_lds.
//   MODE 1: W = stacked [Q(64);K(64)] rows; out position-major Qt/Kt [b][n][64]
//           (Q scaled by log2e). wr=0 waves -> Q, wr=1 -> K.
//   MODE 0: W = wv (rows by blockIdx.y); out natural Vn [b][od][n].
// 256 thr / 4 waves, wave quadrant 64x64, acc[2][2] 32x32 subtiles.
// ---------------------------------------------------------------------------
template <int MODE>
__global__ __launch_bounds__(256, 2) void proj128_kernel(const unsigned short* __restrict__ W,
                                                         const float* __restrict__ bq,
                                                         const float* __restrict__ bk,
                                                         const unsigned short* __restrict__ xT,
                                                         unsigned short* __restrict__ Ya,
                                                         unsigned short* __restrict__ Yb) {
    __shared__ __align__(16) unsigned short Wl[2][128 * 64];
    __shared__ __align__(16) unsigned short Xl[2][128 * 64];
    const int b = blockIdx.z, r0 = blockIdx.y * 128, n0 = blockIdx.x * 128;
    const int tid = threadIdx.x, w = tid >> 6, l = tid & 63, lo = l & 31, hi = l >> 5;
    const int wr = w >> 1, wc = w & 1;

    // staging sources (pre-swizzled: physical chunk p holds logical chunk p^(row&7))
    const unsigned short* wsrc[4];
    const unsigned short* xsrc[4];
    #pragma unroll
    for (int g = 0; g < 4; ++g) {
        int row = g * 32 + w * 8 + (l >> 3);
        int ch = ((l & 7) ^ (row & 7)) << 3;
        wsrc[g] = W + (size_t)(r0 + row) * CDIM + ch;
        xsrc[g] = xT + ((size_t)(b * NPOS + n0 + row)) * CDIM + ch;
    }

    f32x16 acc[2][2];
    #pragma unroll
    for (int a = 0; a < 2; ++a)
        #pragma unroll
        for (int q = 0; q < 16; ++q) { acc[a][0][q] = 0.f; acc[a][1][q] = 0.f; }

    // prologue: stage ck=0 into buf 0
    #pragma unroll
    for (int g = 0; g < 4; ++g) {
        gload_lds16(wsrc[g], &Wl[0][(g * 32 + w * 8) * 64]);
        gload_lds16(xsrc[g], &Xl[0][(g * 32 + w * 8) * 64]);
    }
    __syncthreads();

    for (int t = 0; t < 8; ++t) {
        const int cur = t & 1;
        if (t < 7) {
            #pragma unroll
            for (int g = 0; g < 4; ++g) {
                gload_lds16(wsrc[g] + (t + 1) * 64, &Wl[cur ^ 1][(g * 32 + w * 8) * 64]);
                gload_lds16(xsrc[g] + (t + 1) * 64, &Xl[cur ^ 1][(g * 32 + w * 8) * 64]);
            }
        }
        #pragma unroll
        for (int kc = 0; kc < 4; ++kc) {
            const int cpos = ((2 * kc + hi) ^ (lo & 7)) << 3;
            short8v wa0 = *reinterpret_cast<const short8v*>(&Wl[cur][(wr * 64 + lo) * 64 + cpos]);
            short8v wa1 = *reinterpret_cast<const short8v*>(&Wl[cur][(wr * 64 + 32 + lo) * 64 + cpos]);
            short8v xb0 = *reinterpret_cast<const short8v*>(&Xl[cur][(wc * 64 + lo) * 64 + cpos]);
            short8v xb1 = *reinterpret_cast<const short8v*>(&Xl[cur][(wc * 64 + 32 + lo) * 64 + cpos]);
            acc[0][0] = __builtin_amdgcn_mfma_f32_32x32x16_bf16(wa0, xb0, acc[0][0], 0, 0, 0);
            acc[0][1] = __builtin_amdgcn_mfma_f32_32x32x16_bf16(wa0, xb1, acc[0][1], 0, 0, 0);
            acc[1][0] = __builtin_amdgcn_mfma_f32_32x32x16_bf16(wa1, xb0, acc[1][0], 0, 0, 0);
            acc[1][1] = __builtin_amdgcn_mfma_f32_32x32x16_bf16(wa1, xb1, acc[1][1], 0, 0, 0);
        }
        __syncthreads();
    }

    if (MODE == 1) {
        // wr==0 -> Q (scale log2e, bias bq, Qt); wr==1 -> K (bias bk, Kt)
        const float scale = wr ? 1.0f : 1.44269504f;
        const float* bias = wr ? bk : bq;
        unsigned short* Y = wr ? Yb : Ya;
        #pragma unroll
        for (int a = 0; a < 2; ++a) {
            #pragma unroll
            for (int c = 0; c < 2; ++c) {
                const int n = n0 + wc * 64 + c * 32 + lo;
                #pragma unroll
                for (int g = 0; g < 4; ++g) {
                    int rb = a * 32 + g * 8 + hi * 4;     // local r in [0,64)
                    float4 b4 = *reinterpret_cast<const float4*>(bias + rb);
                    ushort4 u;
                    u.x = f2bf((acc[a][c][4 * g + 0] + b4.x) * scale);
                    u.y = f2bf((acc[a][c][4 * g + 1] + b4.y) * scale);
                    u.z = f2bf((acc[a][c][4 * g + 2] + b4.z) * scale);
                    u.w = f2bf((acc[a][c][4 * g + 3] + b4.w) * scale);
                    *reinterpret_cast<ushort4*>(Y + ((size_t)(b * NPOS + n) * KDQK + rb)) = u;
                }
            }
        }
    } else {
        #pragma unroll
        for (int a = 0; a < 2; ++a) {
            #pragma unroll
            for (int c = 0; c < 2; ++c) {
                const int n = n0 + wc * 64 + c * 32 + lo;
                #pragma unroll
                for (int g = 0; g < 4; ++g) {
                    int rb = r0 + wr * 64 + a * 32 + g * 8 + hi * 4;
                    float4 b4 = *reinterpret_cast<const float4*>(bq + rb);
                    Ya[(size_t)(b * ODIM + rb + 0) * NPOS + n] = f2bf(acc[a][c][4 * g + 0] + b4.x);
                    Ya[(size_t)(b * ODIM + rb + 1) * NPOS + n] = f2bf(acc[a][c][4 * g + 1] + b4.y);
                    Ya[(size_t)(b * ODIM + rb + 2) * NPOS + n] = f2bf(acc[a][c][4 * g + 2] + b4.z);
                    Ya[(size_t)(b * ODIM + rb + 3) * NPOS + n] = f2bf(acc[a][c][4 * g + 3] + b4.w);
                }
            }
        }
    }
}

// ---------------------------------------------------------------------------
// Kernel 4: flash attention + gamma*out + v
//
// Block: 256 thr / 4 waves; QB=128 q x OD=256 (od-half); JB=32; 128 tiles.
// Grid = 32qt x 2odh x 8b = 512 blocks = 2 blocks/CU (LDS 49KB) -> the two
// resident blocks' phases overlap (softmax of one under PV/MFMA of other).
// QK/softmax: wave w owns i-slice [32w,32w+32), m/l per-lane, no duplication;
// P (bf16) + c through LDS. PV register-blocked: wave covers 64i x 128od,
// per kc reads 2 P-frags + 4 V-frags -> 8 mfma (0.75 KB LDS per mfma).
// 64B LDS rows (P, V) use XOR key (row>>1)&3 -> conflict-free b128/int2;
// K rows 128B use key row&7. K/V double-buffered via global_load_lds,
// staged at top of PV, drained by next barrier.
// ---------------------------------------------------------------------------
__global__ __launch_bounds__(256, 2) void attn_kernel(const unsigned short* __restrict__ Qt,
                                                      const unsigned short* __restrict__ Kt,
                                                      const unsigned short* __restrict__ V,
                                                      const float* __restrict__ gamma_p,
                                                      float* __restrict__ out) {
    __shared__ __align__(16) unsigned short Kbuf[2][32 * 64];   // [j][kd] 128B rows, key j&7
    __shared__ __align__(16) unsigned short Vbuf[2][256 * 32];  // [od][j] 64B rows, key (od>>1)&3
    __shared__ __align__(16) unsigned short Pl[128 * 32];       // [i][j]  64B rows, key (i>>1)&3
    __shared__ float cb[128];
    __shared__ float lb[128];

    const int bid = blockIdx.x;
    const int b = bid & 7, r = bid >> 3, odh = r & 1, qt = r >> 1;
    const int i0 = qt * 128, od0 = odh * 256;
    const int tid = threadIdx.x, w = tid >> 6, l = tid & 63, lo = l & 31, hi = l >> 5;
    const int pvw = w >> 1, ow = w & 1;        // PV: i-range [64*pvw,+64), od [128*ow,+128)
    const int keyr = (lo >> 1) & 3;            // read-side key for 64B-row tiles

    // ---- staging sources (pre-swizzled)
    const int krow = w * 8 + (l >> 3);
    const unsigned short* kp = Kt + ((size_t)b * NPOS + krow) * KDQK + (((l & 7) ^ (krow & 7)) << 3);
    const unsigned short* vp[4];
    #pragma unroll
    for (int v = 0; v < 4; ++v) {
        int vrow = v * 64 + w * 16 + (l >> 2);
        vp[v] = V + ((size_t)(b * ODIM + od0 + vrow)) * NPOS + (((l & 3) ^ ((vrow >> 1) & 3)) << 3);
    }

    // ---- Q fragments (B-operand: lane = query col i = 32w+lo)
    short8v qf[4];
    {
        const unsigned short* qb = Qt + ((size_t)b * NPOS + i0 + w * 32 + lo) * KDQK + hi * 8;
        #pragma unroll
        for (int kc = 0; kc < 4; ++kc)
            qf[kc] = *reinterpret_cast<const short8v*>(qb + kc * 16);
    }

    f32x16 acc[2][4];
    #pragma unroll
    for (int it = 0; it < 2; ++it)
        #pragma unroll
        for (int odg = 0; odg < 4; ++odg)
            #pragma unroll
            for (int q = 0; q < 16; ++q) acc[it][odg][q] = 0.f;

    float m_run = -1e30f, l_run = 0.f;

    // prologue: stage tile 0 into buf 0
    gload_lds16(kp, &Kbuf[0][w * 512]);
    #pragma unroll
    for (int v = 0; v < 4; ++v) gload_lds16(vp[v], &Vbuf[0][(v * 64 + w * 16) * 32]);
    __syncthreads();

    for (int t = 0; t < NPOS / 32; ++t) {
        const int cur = t & 1;

        // ---------------- Phase A: QK^T + in-wave softmax + P/cb write --------
        f32x16 s;
        #pragma unroll
        for (int q = 0; q < 16; ++q) s[q] = 0.f;
        const unsigned short* KB = &Kbuf[cur][0];
        #pragma unroll
        for (int kc = 0; kc < 4; ++kc) {
            short8v a = *reinterpret_cast<const short8v*>(
                KB + lo * 64 + (((2 * kc + hi) ^ (lo & 7)) << 3));
            s = __builtin_amdgcn_mfma_f32_32x32x16_bf16(a, qf[kc], s, 0, 0, 0);
        }
        float mx = s[0];
        #pragma unroll
        for (int q = 1; q < 16; ++q) mx = fmaxf(mx, s[q]);
        mx = fmaxf(mx, __shfl_xor(mx, 32));

        bool g = mx > m_run + 12.f;             // defer-max (log2 domain)
        float c = g ? exp2_raw(m_run - mx) : 1.f;
        if (g) m_run = mx;

        float rs = 0.f;
        #pragma unroll
        for (int q = 0; q < 16; ++q) { s[q] = exp2_raw(s[q] - m_run); rs += s[q]; }
        rs += __shfl_xor(rs, 32);
        l_run = l_run * c + rs;
        if (hi == 0) cb[w * 32 + lo] = c;

        {   // P write: row i = 32w+lo; reg q -> j = (q&3)+8(q>>2)+4hi
            unsigned short* prow = &Pl[(w * 32 + lo) * 32];
            #pragma unroll
            for (int m = 0; m < 4; ++m) {
                int w0 = cvtpk(s[4 * m + 0], s[4 * m + 1]);
                int w1 = cvtpk(s[4 * m + 2], s[4 * m + 3]);
                *reinterpret_cast<int2*>(prow + ((m ^ keyr) << 3) + hi * 4) = make_int2(w0, w1);
            }
        }
        __syncthreads();   // B1: P/cb visible; everyone past PV(t-1)

        // ---------------- Phase C: stage t+1, rescale, PV ----------------
        if (t + 1 < NPOS / 32) {
            const int nb = cur ^ 1;
            gload_lds16(kp + (size_t)(t + 1) * 2048, &Kbuf[nb][w * 512]);
            #pragma unroll
            for (int v = 0; v < 4; ++v)
                gload_lds16(vp[v] + (t + 1) * 32, &Vbuf[nb][(v * 64 + w * 16) * 32]);
        }

        float cv0 = cb[pvw * 64 + lo];
        float cv1 = cb[pvw * 64 + 32 + lo];
        if (__any(cv0 != 1.f || cv1 != 1.f)) {
            #pragma unroll
            for (int odg = 0; odg < 4; ++odg)
                #pragma unroll
                for (int q = 0; q < 16; ++q) { acc[0][odg][q] *= cv0; acc[1][odg][q] *= cv1; }
        }

        const unsigned short* VB = &Vbuf[cur][0];
        #pragma unroll
        for (int kc = 0; kc < 2; ++kc) {
            const int cpos = (((2 * kc + hi) ^ keyr) << 3);
            short8v pb0 = *reinterpret_cast<const short8v*>(&Pl[(pvw * 64 + lo) * 32] + cpos);
            short8v pb1 = *reinterpret_cast<const short8v*>(&Pl[(pvw * 64 + 32 + lo) * 32] + cpos);
            #pragma unroll
            for (int odg = 0; odg < 4; ++odg) {
                short8v va = *reinterpret_cast<const short8v*>(
                    VB + (ow * 128 + odg * 32 + lo) * 32 + cpos);
                acc[0][odg] = __builtin_amdgcn_mfma_f32_32x32x16_bf16(va, pb0, acc[0][odg], 0, 0, 0);
                acc[1][odg] = __builtin_amdgcn_mfma_f32_32x32x16_bf16(va, pb1, acc[1][odg], 0, 0, 0);
            }
        }
        __syncthreads();   // B2: drains stage vmem, guards P/Kbuf/Vbuf WAR
    }

    // ---------------- epilogue: out = gamma*O/l + v ----------------
    if (hi == 0) lb[w * 32 + lo] = l_run;
    __syncthreads();
    float linv0 = 1.0f / lb[pvw * 64 + lo];
    float linv1 = 1.0f / lb[pvw * 64 + 32 + lo];
    const float gm = gamma_p[0];
    #pragma unroll
    for (int it = 0; it < 2; ++it) {
        float linv = it ? linv1 : linv0;
        #pragma unroll
        for (int odg = 0; odg < 4; ++odg) {
            #pragma unroll
            for (int q = 0; q < 16; ++q) {
                int od = od0 + ow * 128 + odg * 32 + (q & 3) + 8 * (q >> 2) + 4 * hi;
                int i = i0 + pvw * 64 + it * 32 + lo;
                size_t addr = ((size_t)b * ODIM + od) * NPOS + i;
                out[addr] = gm * acc[it][odg][q] * linv + bf2f(V[addr]);
            }
        }
    }
}

// ---------------------------------------------------------------------------
// Host launcher
// ---------------------------------------------------------------------------
extern "C" void kernel_launch(void* const* d_in, const int* in_sizes, int n_in,
                              void* d_out, int out_size, void* d_ws, size_t ws_size,
                              hipStream_t stream) {
    const float* x     = (const float*)d_in[0];
    const float* qw    = (const float*)d_in[1];
    const float* qb    = (const float*)d_in[2];
    const float* kw    = (const float*)d_in[3];
    const float* kb    = (const float*)d_in[4];
    const float* vw    = (const float*)d_in[5];
    const float* vb    = (const float*)d_in[6];
    const float* gamma = (const float*)d_in[7];
    float* out = (float*)d_out;

    char* ws = (char*)d_ws;
    unsigned short* xT = (unsigned short*)(ws);                  // 33,554,432  [B][N][C] bf16
    unsigned short* wq = (unsigned short*)(ws + 33554432);       //     65,536  (wq|wk contiguous)
    unsigned short* wk = (unsigned short*)(ws + 33619968);       //     65,536
    unsigned short* wv = (unsigned short*)(ws + 33685504);       //    524,288
    unsigned short* Qt = (unsigned short*)(ws + 34209792);       //  4,194,304  [B][N][64] (x log2e)
    unsigned short* Kt = (unsigned short*)(ws + 38404096);       //  4,194,304  [B][N][64]
    unsigned short* Vn = (unsigned short*)(ws + 42598400);       // 33,554,432  [B][512][N]

    wconv_kernel<<<1280, 256, 0, stream>>>(qw, kw, vw, wq, wk, wv);
    xpose_kernel<<<dim3(64, 8, 8), 256, 0, stream>>>(x, xT);
    // fused Q+K projection (stacked 128-row weight), position-major outputs
    proj128_kernel<1><<<dim3(32, 1, 8), 256, 0, stream>>>(wq, qb, kb, xT, Qt, Kt);
    // V projection, natural layout
    proj128_kernel<0><<<dim3(32, 4, 8), 256, 0, stream>>>(wv, vb, vb, xT, Vn, Vn);
    attn_kernel<<<512, 256, 0, stream>>>(Qt, Kt, Vn, gamma, out);
}